// Round 5
// baseline (153.188 us; speedup 1.0000x reference)
//
#include <hip/hip_runtime.h>
#include <cfloat>
#include <cstdint>
#include <cstddef>

using u16 = unsigned short;
typedef __attribute__((ext_vector_type(8))) short short8;
typedef __attribute__((ext_vector_type(4))) float f32x4;

#define HEADS 6
#define NSEQ 4096
#define SCALEF 0.125f
#define LOG2E 1.4426950408889634f
#define SC2 (SCALEF * LOG2E)

#if __has_builtin(__builtin_amdgcn_exp2f)
#define EXP2(x) __builtin_amdgcn_exp2f(x)
#else
#define EXP2(x) exp2f(x)
#endif

__device__ __forceinline__ f32x4 vmin4(f32x4 a, f32x4 b) {
#if __has_builtin(__builtin_elementwise_min)
  return __builtin_elementwise_min(a, b);
#else
  f32x4 r; for (int i = 0; i < 4; ++i) r[i] = fminf(a[i], b[i]); return r;
#endif
}
__device__ __forceinline__ f32x4 vmax4(f32x4 a, f32x4 b) {
#if __has_builtin(__builtin_elementwise_max)
  return __builtin_elementwise_max(a, b);
#else
  f32x4 r; for (int i = 0; i < 4; ++i) r[i] = fmaxf(a[i], b[i]); return r;
#endif
}

__device__ __forceinline__ u16 f2bf_rn(float f) {
  unsigned int u = __builtin_bit_cast(unsigned int, f);
  u = (u + 0x7FFFu + ((u >> 16) & 1u)) >> 16;
  return (u16)u;
}

__device__ __forceinline__ void gload_lds16(const void* g, void* l) {
  __builtin_amdgcn_global_load_lds((const __attribute__((address_space(1))) void*)g,
                                   (__attribute__((address_space(3))) void*)l, 16, 0, 0);
}

// Swizzled b128 read from a [rows][64] u16 LDS tile (128B rows). (GEMM use)
__device__ __forceinline__ short8 frag_read(const u16* tile, int row, int blk) {
  int byt = row * 128 + ((blk * 16) ^ ((row & 7) << 4));
  return *(const short8*)((const char*)tile + byt);
}

__global__ void cast_kernel(const float* __restrict__ src, u16* __restrict__ dst, int n8) {
  int i = blockIdx.x * blockDim.x + threadIdx.x;
  if (i >= n8) return;
  const float4* s = (const float4*)src;
  float4 a = s[2 * i], b = s[2 * i + 1];
  short8 r;
  r[0] = (short)f2bf_rn(a.x); r[1] = (short)f2bf_rn(a.y);
  r[2] = (short)f2bf_rn(a.z); r[3] = (short)f2bf_rn(a.w);
  r[4] = (short)f2bf_rn(b.x); r[5] = (short)f2bf_rn(b.y);
  r[6] = (short)f2bf_rn(b.z); r[7] = (short)f2bf_rn(b.w);
  ((short8*)dst)[i] = r;
}

__global__ void mask_addend_kernel(const int* __restrict__ m, float* __restrict__ out, int n) {
  int i = blockIdx.x * blockDim.x + threadIdx.x;
  if (i < n) out[i] = m[i] ? 0.f : -FLT_MAX;
}

// C = A(MxK) * B(NxK)^T ; 128x128 tile, BK=64, 4 waves (2x2 of 64x64).
template <int EPI>
__launch_bounds__(256)
__global__ void gemm_bt(const u16* __restrict__ A, const u16* __restrict__ B,
                        int Kdim, int Ndim,
                        u16* __restrict__ q_out, u16* __restrict__ k_out, u16* __restrict__ vt_out,
                        const float* __restrict__ bias, float* __restrict__ out) {
  __shared__ u16 lA[128 * 64];
  __shared__ u16 lB[128 * 64];
  int brow = blockIdx.x, bcol = blockIdx.y;
  int tid = threadIdx.x;
  int w = tid >> 6, lane = tid & 63;
  int wr = w >> 1, wc = w & 1;
  int r_in = lane >> 3;
  int jblk = (lane & 7) ^ r_in;
  int l15 = lane & 15, lg = lane >> 4;

  f32x4 acc[4][4];
#pragma unroll
  for (int i = 0; i < 4; i++)
#pragma unroll
    for (int j = 0; j < 4; j++) acc[i][j] = (f32x4){0.f, 0.f, 0.f, 0.f};

  const u16* Ab = A + (size_t)(brow * 128 + w * 32 + r_in) * Kdim + jblk * 8;
  const u16* Bb = B + (size_t)(bcol * 128 + w * 32 + r_in) * Kdim + jblk * 8;

  int ksteps = Kdim >> 6;
  for (int kt = 0; kt < ksteps; ++kt) {
    __syncthreads();
#pragma unroll
    for (int c = 0; c < 4; ++c) {
      gload_lds16(Ab + kt * 64 + (size_t)(c * 8) * Kdim, &lA[(w * 32 + c * 8) * 64]);
      gload_lds16(Bb + kt * 64 + (size_t)(c * 8) * Kdim, &lB[(w * 32 + c * 8) * 64]);
    }
    asm volatile("s_waitcnt vmcnt(0)" ::: "memory");
    __syncthreads();

    short8 af[4][2], bfr[4][2];
#pragma unroll
    for (int ms = 0; ms < 4; ++ms)
#pragma unroll
      for (int hf = 0; hf < 2; ++hf)
        af[ms][hf] = frag_read(lA, wr * 64 + ms * 16 + l15, hf * 4 + lg);
#pragma unroll
    for (int ns = 0; ns < 4; ++ns)
#pragma unroll
      for (int hf = 0; hf < 2; ++hf)
        bfr[ns][hf] = frag_read(lB, wc * 64 + ns * 16 + l15, hf * 4 + lg);
#pragma unroll
    for (int ms = 0; ms < 4; ++ms)
#pragma unroll
      for (int ns = 0; ns < 4; ++ns) {
        acc[ms][ns] = __builtin_amdgcn_mfma_f32_16x16x32_bf16(af[ms][0], bfr[ns][0], acc[ms][ns], 0, 0, 0);
        acc[ms][ns] = __builtin_amdgcn_mfma_f32_16x16x32_bf16(af[ms][1], bfr[ns][1], acc[ms][ns], 0, 0, 0);
      }
  }

#pragma unroll
  for (int ms = 0; ms < 4; ++ms)
#pragma unroll
    for (int ns = 0; ns < 4; ++ns)
#pragma unroll
      for (int r = 0; r < 4; ++r) {
        int row_g = brow * 128 + wr * 64 + ms * 16 + lg * 4 + r;
        int col_g = bcol * 128 + wc * 64 + ns * 16 + l15;
        float v = acc[ms][ns][r];
        if (EPI == 0) {
          int t = col_g / 384;
          int rem = col_g - t * 384;
          int h = rem >> 6, d = rem & 63;
          int b = row_g >> 12, n = row_g & 4095;
          u16 val = f2bf_rn(v);
          size_t bh = (size_t)(b * HEADS + h);
          if (t == 0)      q_out[(bh * NSEQ + n) * 64 + d] = val;
          else if (t == 1) k_out[(bh * NSEQ + n) * 64 + d] = val;
          else             vt_out[(bh * 64 + d) * NSEQ + n] = val;
        } else {
          out[(size_t)row_g * Ndim + col_g] = v + bias[col_g];
        }
      }
}

// Flash attention, swapped-operand, KT=128, single 32KB buffer staged via
// global_load_lds (pre-swizzled per-lane source, linear dest — proven pattern).
// 256 thr = 4 waves x 16 q-rows.
__launch_bounds__(256, 3)
__global__ void attn_kernel(const u16* __restrict__ qg, const u16* __restrict__ kg,
                            const u16* __restrict__ vtg, const float* __restrict__ madd,
                            u16* __restrict__ attn_out) {
  __shared__ u16 lK[128 * 64];   // [k_local][d], 128B rows, XOR key = row&7
  __shared__ u16 lV[64 * 128];   // [d][k_local], 256B rows, XOR key = row&15

  // bijective XCD swizzle: 768 blocks, 96 per XCD, contiguous bh-major work per XCD
  int bid = blockIdx.y * 64 + blockIdx.x;
  int orig = (bid & 7) * 96 + (bid >> 3);
  int qb = orig & 63, bh = orig >> 6;

  int b = bh / HEADS, h = bh - b * HEADS;
  int q0 = qb * 64;
  int tid = threadIdx.x;
  int w = tid >> 6, lane = tid & 63;
  int l15 = lane & 15, lg = lane >> 4;
  int r_in = lane >> 3, jblk = (lane & 7) ^ r_in;

  const u16* Q = qg + (size_t)bh * NSEQ * 64;
  const u16* K = kg + (size_t)bh * NSEQ * 64;
  const u16* VT = vtg + (size_t)bh * 64 * NSEQ;
  const float* marow = madd + b * NSEQ;

  int qrow = q0 + w * 16 + l15;
  short8 qf[2];
#pragma unroll
  for (int hf = 0; hf < 2; ++hf)
    qf[hf] = *(const short8*)(Q + (size_t)qrow * 64 + hf * 32 + lg * 8);

  float aqf = marow[qrow];                       // 0 or -FLT_MAX
  f32x4 aqf4 = (f32x4){aqf, aqf, aqf, aqf};

  // lane-constant swizzled read offsets
  int swk = (l15 & 7) << 4;
  int offKA = l15 * 128 + ((lg * 16) ^ swk);
  int offKB = l15 * 128 + (((4 + lg) * 16) ^ swk);
  int voff[4];
#pragma unroll
  for (int c = 0; c < 4; ++c)
    voff[c] = l15 * 256 + ((((c * 4 + lg) ^ l15)) << 4);

  f32x4 acc[4];  // O^T: acc[ds][r] = O[d = ds*16 + lg*4 + r][q = qrow]
#pragma unroll
  for (int ds_ = 0; ds_ < 4; ++ds_) acc[ds_] = (f32x4){0.f, 0.f, 0.f, 0.f};
  float m2 = -INFINITY, l_r = 0.f;

  // STAGE via global_load_lds, linear dest + per-lane pre-swizzled source:
  //  lK: wave rows [w*32+c*8, +8): lane -> row krb+r_in, dest blk lane&7,
  //      src blk jblk = (lane&7)^r_in   (row&7 == r_in since krb%8==0)
  //  lV: wave rows [w*16+c*4, +4): lane -> row vrb+lg, dest blk l15,
  //      src blk l15 ^ ((vrb+lg)&15) = l15 ^ (c*4+lg)  (vrb%16 == c*4)
#define STAGE(k0s)                                                                    \
  {                                                                                   \
    _Pragma("unroll")                                                                 \
    for (int c = 0; c < 4; ++c) {                                                     \
      int krb = w * 32 + c * 8;                                                       \
      gload_lds16(K + (size_t)((k0s) + krb + r_in) * 64 + jblk * 8, &lK[krb * 64]);   \
      int vrb = w * 16 + c * 4;                                                       \
      int vsb = l15 ^ (c * 4 + lg);                                                   \
      gload_lds16(VT + (size_t)(vrb + lg) * NSEQ + (k0s) + vsb * 8, &lV[vrb * 128]);  \
    }                                                                                 \
  }

  STAGE(0);
  asm volatile("s_waitcnt vmcnt(0)" ::: "memory");
  __syncthreads();

  const int NT = NSEQ / 128;
  for (int t = 0; t < NT; ++t) {
    int k0 = t * 128;

    // S^T = K Q^T : p[cs][r] = S[q = qrow][k = k0 + cs*16 + lg*4 + r]
    f32x4 p[8];
    __builtin_amdgcn_s_setprio(1);
#pragma unroll
    for (int cs = 0; cs < 8; ++cs) {
      short8 kf0 = *(const short8*)((const char*)lK + offKA + cs * 2048);
      short8 kf1 = *(const short8*)((const char*)lK + offKB + cs * 2048);
      f32x4 z = (f32x4){0.f, 0.f, 0.f, 0.f};
      z = __builtin_amdgcn_mfma_f32_16x16x32_bf16(kf0, qf[0], z, 0, 0, 0);
      p[cs] = __builtin_amdgcn_mfma_f32_16x16x32_bf16(kf1, qf[1], z, 0, 0, 0);
    }
    __builtin_amdgcn_s_setprio(0);

    // log2-space pre-softmax with inline mask addend
#pragma unroll
    for (int cs = 0; cs < 8; ++cs) {
      f32x4 mf = *(const f32x4*)(marow + k0 + cs * 16 + lg * 4);
      p[cs] = p[cs] * SC2 + vmin4(mf, aqf4);
    }

    // row max over 32 elems + 2 shuffles
    f32x4 t4 = vmax4(vmax4(vmax4(p[0], p[1]), vmax4(p[2], p[3])),
                     vmax4(vmax4(p[4], p[5]), vmax4(p[6], p[7])));
    float tm = fmaxf(fmaxf(t4[0], t4[1]), fmaxf(t4[2], t4[3]));
    tm = fmaxf(tm, __shfl_xor(tm, 16));
    tm = fmaxf(tm, __shfl_xor(tm, 32));

    // T13 defer-rescale (THR=8)
    if (!__all(tm <= m2 + 8.0f)) {
      float mnew = fmaxf(m2, tm);
      float corr = EXP2(m2 - mnew);
      m2 = mnew;
      l_r *= corr;
#pragma unroll
      for (int ds_ = 0; ds_ < 4; ++ds_) acc[ds_] *= corr;
    }

    // p = exp2(p - m2)
#pragma unroll
    for (int cs = 0; cs < 8; ++cs) {
      f32x4 d = p[cs] - m2;
#pragma unroll
      for (int r = 0; r < 4; ++r) p[cs][r] = EXP2(d[r]);
    }
    f32x4 s4 = ((p[0] + p[1]) + (p[2] + p[3])) + ((p[4] + p[5]) + (p[6] + p[7]));
    float rsum = (s4[0] + s4[1]) + (s4[2] + s4[3]);
    rsum += __shfl_xor(rsum, 16);
    rsum += __shfl_xor(rsum, 32);
    l_r += rsum;

    // P^T -> bf16 packed words
    uint32_t wd[8][2];
#pragma unroll
    for (int cs = 0; cs < 8; ++cs)
#pragma unroll
      for (int hh = 0; hh < 2; ++hh)
        asm("v_cvt_pk_bf16_f32 %0, %1, %2" : "=v"(wd[cs][hh]) : "v"(p[cs][2 * hh]), "v"(p[cs][2 * hh + 1]));

    // permlane dance -> PV B-operand fragments (4 chunks of 32 k)
    short8 pf[4];
#pragma unroll
    for (int c = 0; c < 4; ++c) {
      union { uint32_t u[4]; short8 s8; } cv;
#pragma unroll
      for (int hh = 0; hh < 2; ++hh) {
        uint32_t A = wd[2 * c][hh], B = wd[2 * c + 1][hh];
        asm("v_permlane32_swap_b32 %0, %1" : "+v"(A), "+v"(B));
        asm("v_permlane16_swap_b32 %0, %1" : "+v"(A), "+v"(B));
        cv.u[hh] = A;
        cv.u[2 + hh] = B;
      }
      pf[c] = cv.s8;
    }

    // O^T += V^T P^T  (reduction over 128 k in 4 chunks)
    __builtin_amdgcn_s_setprio(1);
#pragma unroll
    for (int ds_ = 0; ds_ < 4; ++ds_) {
#pragma unroll
      for (int c = 0; c < 4; ++c) {
        short8 vf = *(const short8*)((const char*)lV + voff[c] + ds_ * 4096);
        acc[ds_] = __builtin_amdgcn_mfma_f32_16x16x32_bf16(vf, pf[c], acc[ds_], 0, 0, 0);
      }
    }
    __builtin_amdgcn_s_setprio(0);

    __syncthreads();                  // all waves done reading tile t
    if (t + 1 < NT) {
      STAGE(k0 + 128);                // refill same buffer
      asm volatile("s_waitcnt vmcnt(0)" ::: "memory");
      __syncthreads();                // all loads landed before next reads
    }
  }

  // epilogue: attn_out[b, n=qrow, h*64 + d] = O^T[d][qrow] / l
  float inv = 1.0f / l_r;
  size_t base = ((size_t)b * NSEQ + qrow) * 384 + h * 64;
#pragma unroll
  for (int ds_ = 0; ds_ < 4; ++ds_) {
    uint32_t w0, w1;
    float a0 = acc[ds_][0] * inv, a1 = acc[ds_][1] * inv;
    float a2 = acc[ds_][2] * inv, a3 = acc[ds_][3] * inv;
    asm("v_cvt_pk_bf16_f32 %0, %1, %2" : "=v"(w0) : "v"(a0), "v"(a1));
    asm("v_cvt_pk_bf16_f32 %0, %1, %2" : "=v"(w1) : "v"(a2), "v"(a3));
    uint2 st; st.x = w0; st.y = w1;
    *(uint2*)(attn_out + base + ds_ * 16 + lg * 4) = st;
  }
#undef STAGE
}

extern "C" void kernel_launch(void* const* d_in, const int* in_sizes, int n_in,
                              void* d_out, int out_size, void* d_ws, size_t ws_size,
                              hipStream_t stream) {
  const float* x = (const float*)d_in[0];
  const int* mask = (const int*)d_in[1];
  const float* w_qkv = (const float*)d_in[2];
  const float* w_proj = (const float*)d_in[3];
  const float* b_proj = (const float*)d_in[4];
  float* out = (float*)d_out;

  char* ws = (char*)d_ws;
  u16* x_bf = (u16*)(ws + 0);              //  8192x384
  u16* wqkv_bf = (u16*)(ws + 6291456);     //  1152x384
  u16* wproj_bf = (u16*)(ws + 7176192);    //   384x384
  u16* q_bf = (u16*)(ws + 7471104);        //  [b,h,n,d]
  u16* k_bf = (u16*)(ws + 13762560);       //  [b,h,n,d]
  u16* vt_bf = (u16*)(ws + 20054016);      //  [b,h,d,n]
  u16* attn_bf = (u16*)(ws + 26345472);    //  8192x384
  float* madd = (float*)(ws + 32636928);   //  [2][4096] f32

  cast_kernel<<<(3145728 / 8 + 255) / 256, 256, 0, stream>>>(x, x_bf, 3145728 / 8);
  cast_kernel<<<(442368 / 8 + 255) / 256, 256, 0, stream>>>(w_qkv, wqkv_bf, 442368 / 8);
  cast_kernel<<<(147456 / 8 + 255) / 256, 256, 0, stream>>>(w_proj, wproj_bf, 147456 / 8);
  mask_addend_kernel<<<32, 256, 0, stream>>>(mask, madd, 2 * NSEQ);

  gemm_bt<0><<<dim3(64, 9), 256, 0, stream>>>(x_bf, wqkv_bf, 384, 1152,
                                              q_bf, k_bf, vt_bf, nullptr, nullptr);
  attn_kernel<<<dim3(64, 12), 256, 0, stream>>>(q_bf, k_bf, vt_bf, madd, attn_bf);
  gemm_bt<1><<<dim3(64, 3), 256, 0, stream>>>(attn_bf, wproj_bf, 384, 384,
                                              nullptr, nullptr, nullptr, b_proj, out);
}